// Round 4
// baseline (729.226 us; speedup 1.0000x reference)
//
#include <hip/hip_runtime.h>
#include <hip/hip_bf16.h>

typedef unsigned short u16;
typedef u16   u16x4 __attribute__((ext_vector_type(4)));
typedef u16   u16x8 __attribute__((ext_vector_type(8)));
typedef short v8s   __attribute__((ext_vector_type(8)));   // 8 bf16 bits for MFMA A/B
typedef float fx4   __attribute__((ext_vector_type(4)));

#define DEVINL __device__ __forceinline__

DEVINL u16 f2bf(float x){                 // round-to-nearest-even fp32 -> bf16
    unsigned u = __float_as_uint(x);
    u = u + 0x7FFFu + ((u >> 16) & 1u);
    return (u16)(u >> 16);
}
DEVINL float bf2f(u16 h){ return __uint_as_float(((unsigned)h) << 16); }

// async global -> LDS, 16B per lane (dest = wave-uniform base + lane*16)
DEVINL void gload16(const u16* g, u16* l){
    __builtin_amdgcn_global_load_lds(
        (const __attribute__((address_space(1))) void*)g,
        (__attribute__((address_space(3))) void*)l, 16, 0, 0);
}

// ---------------- conversion: z (fp32) -> Z[8192][2048] bf16 hi/lo ---------
__global__ void convZ_kernel(const float* __restrict__ zr, const float* __restrict__ zi,
                             u16* __restrict__ Zh, u16* __restrict__ Zl){
    int idx = blockIdx.x * blockDim.x + threadIdx.x;   // one float4 each
    size_t i4 = (size_t)idx * 4;
    int m = (int)(i4 >> 11);
    int c = (int)(i4 & 2047);
    const float* src = (c < 1024) ? (zr + (size_t)m*1024 + c)
                                  : (zi + (size_t)m*1024 + (c - 1024));
    fx4 v = *(const fx4*)src;
    u16x4 h, l;
#pragma unroll
    for (int j = 0; j < 4; j++){
        u16 hh = f2bf(v[j]); h[j] = hh; l[j] = f2bf(v[j] - bf2f(hh));
    }
    *(u16x4*)(Zh + i4) = h;
    *(u16x4*)(Zl + i4) = l;
}

// ------- conversion: W* (fp32 [1024][512]) -> Wt[3072][2048] bf16 hi/lo -----
__global__ void convW_kernel(const float* __restrict__ Wq_r, const float* __restrict__ Wq_i,
                             const float* __restrict__ Wk_r, const float* __restrict__ Wk_i,
                             const float* __restrict__ Wv_r, const float* __restrict__ Wv_i,
                             u16* __restrict__ Wth, u16* __restrict__ Wtl){
    __shared__ float t[32][33];
    int k0 = blockIdx.x * 32;          // 0..2047
    int c0 = blockIdx.y * 32;          // 0..3071
    int blk = c0 >> 9;  int j0 = c0 & 511;
    int pair = blk >> 1, ri = blk & 1;
    int hh = k0 >> 10;  int ks0 = k0 & 1023;
    const float* Ws[6] = {Wq_r, Wq_i, Wk_r, Wk_i, Wv_r, Wv_i};
    const float* src; float sign = 1.f;
    if (ri == 0){ if (hh == 0) src = Ws[pair*2]; else { src = Ws[pair*2+1]; sign = -1.f; } }
    else        { src = (hh == 0) ? Ws[pair*2+1] : Ws[pair*2]; }
    int tx = threadIdx.x, ty = threadIdx.y;
    for (int yy = ty; yy < 32; yy += 8)
        t[yy][tx] = src[(size_t)(ks0 + yy)*512 + j0 + tx];
    __syncthreads();
    for (int yy = ty; yy < 32; yy += 8){
        float v = sign * t[tx][yy];
        u16 h2 = f2bf(v);
        size_t o = (size_t)(c0 + yy)*2048 + k0 + tx;
        Wth[o] = h2;
        Wtl[o] = f2bf(v - bf2f(h2));
    }
}

// ------ prep: qs = qr+qi, kd = kr-ki (hi/lo), from C hi/lo ------------------
__global__ void prep_kernel(const u16* __restrict__ Chi, const u16* __restrict__ Clo,
                            u16* __restrict__ qsh, u16* __restrict__ qsl,
                            u16* __restrict__ kdh, u16* __restrict__ kdl){
    int idx = blockIdx.x * blockDim.x + threadIdx.x;   // 4 cols of one row
    size_t i4 = (size_t)idx * 4;
    int m = (int)(i4 >> 9); int c = (int)(i4 & 511);
    size_t base = (size_t)m * 3072 + c;
    u16x4 qrh = *(const u16x4*)(Chi + base),        qrl = *(const u16x4*)(Clo + base);
    u16x4 qih = *(const u16x4*)(Chi + base + 512),  qil = *(const u16x4*)(Clo + base + 512);
    u16x4 krh = *(const u16x4*)(Chi + base + 1024), krl = *(const u16x4*)(Clo + base + 1024);
    u16x4 kih = *(const u16x4*)(Chi + base + 1536), kil = *(const u16x4*)(Clo + base + 1536);
    u16x4 oqh, oql, okh, okl;
#pragma unroll
    for (int j = 0; j < 4; j++){
        float qs = (bf2f(qrh[j]) + bf2f(qrl[j])) + (bf2f(qih[j]) + bf2f(qil[j]));
        float kd = (bf2f(krh[j]) + bf2f(krl[j])) - (bf2f(kih[j]) + bf2f(kil[j]));
        u16 h1 = f2bf(qs); oqh[j] = h1; oql[j] = f2bf(qs - bf2f(h1));
        u16 h2 = f2bf(kd); okh[j] = h2; okl[j] = f2bf(kd - bf2f(h2));
    }
    *(u16x4*)(qsh + i4) = oqh;  *(u16x4*)(qsl + i4) = oql;
    *(u16x4*)(kdh + i4) = okh;  *(u16x4*)(kdl + i4) = okl;
}

// ---------------- Vt[b][d][t] = C[(b*2048+t)*3072 + colOff + d] -------------
__global__ void vt_kernel(const u16* __restrict__ C, int colOff, u16* __restrict__ Vt){
    __shared__ u16 t[32][34];
    int t0 = blockIdx.x * 32; int d0 = blockIdx.y * 32; int b = blockIdx.z;
    int tx = threadIdx.x, ty = threadIdx.y;
    const u16* src = C + (size_t)b*2048*3072 + colOff;
    for (int yy = ty; yy < 32; yy += 8)
        t[yy][tx] = src[(size_t)(t0 + yy)*3072 + d0 + tx];
    __syncthreads();
    u16* dst = Vt + (size_t)b*512*2048;
    for (int yy = ty; yy < 32; yy += 8)
        dst[(size_t)(d0 + yy)*2048 + t0 + tx] = t[tx][yy];
}

// ------ fused hybrid + row softmax (2048 cols), writes fp32 + bf16 ----------
__global__ __launch_bounds__(256)
void softmax_kernel(float* __restrict__ H, const float* __restrict__ SiP, u16* __restrict__ Wbf){
    int row = blockIdx.x;
    float* p = H + (size_t)row * 2048;
    const float* q = SiP + (size_t)row * 2048;
    int tid = threadIdx.x;
    fx4 v[2];
#pragma unroll
    for (int i = 0; i < 2; i++){
        fx4 sr = *(fx4*)(p + i*1024 + tid*4);
        fx4 si = *(const fx4*)(q + i*1024 + tid*4);
#pragma unroll
        for (int j = 0; j < 4; j++){
            float mag = sqrtf(sr[j]*sr[j] + si[j]*si[j]);
            float ph  = sr[j] / fmaxf(mag, 1e-30f);
            v[i][j] = (mag + 0.3f*ph) * 0.044194173824159216f;   // 1/sqrt(512)
        }
    }
    float m = -1e30f;
#pragma unroll
    for (int i = 0; i < 2; i++)
#pragma unroll
        for (int j = 0; j < 4; j++) m = fmaxf(m, v[i][j]);
    for (int k = 1; k < 64; k <<= 1) m = fmaxf(m, __shfl_xor(m, k));
    __shared__ float sm[4], ss[4];
    int w = tid >> 6, lane = tid & 63;
    if (lane == 0) sm[w] = m;
    __syncthreads();
    m = fmaxf(fmaxf(sm[0], sm[1]), fmaxf(sm[2], sm[3]));
    float s = 0.f;
#pragma unroll
    for (int i = 0; i < 2; i++)
#pragma unroll
        for (int j = 0; j < 4; j++){ v[i][j] = __expf(v[i][j] - m); s += v[i][j]; }
    for (int k = 1; k < 64; k <<= 1) s += __shfl_xor(s, k);
    if (lane == 0) ss[w] = s;
    __syncthreads();
    s = ss[0] + ss[1] + ss[2] + ss[3];
    float inv = 1.f / s;
    u16* wb = Wbf + (size_t)row * 2048;
#pragma unroll
    for (int i = 0; i < 2; i++){
        fx4 o; u16x4 ob;
#pragma unroll
        for (int j = 0; j < 4; j++){ o[j] = v[i][j] * inv; ob[j] = f2bf(o[j]); }
        *(fx4*)(p + i*1024 + tid*4) = o;
        *(u16x4*)(wb + i*1024 + tid*4) = ob;
    }
}

// ---------------- GEMM: C = A * B^T (bf16 MFMA, optional hi/lo split) -------
// A: [M][lda] rows along K, B: [N][ldb] rows along K. M,N mult of 128, K mult of 64.
// BK=64; LDS tiles [128 rows][64 u16], XOR-swizzled (phys slot = log slot ^ (row&7)).
// SPLIT=1: C ~= Ah*Bh + Ah*Bl + Al*Bh (bf16x3, ~fp32 accurate)
// EPI=0: fp32 write (elem stride ostride)   EPI=1: hi/lo bf16 out
// EPI=2: fp32 accumulate Cf += acc          EPI=3: dual: Cf = Cf+acc, Cg = acc-Cf_old
template<int SPLIT, int EPI>
__global__ __launch_bounds__(256, 2)
void gemm_bt(const u16* __restrict__ Ah, const u16* __restrict__ Al,
             long long aBatch, int lda,
             const u16* __restrict__ Bh, const u16* __restrict__ Bl,
             long long bBatch, int ldb,
             float* __restrict__ Cf, float* __restrict__ Cg,
             u16* __restrict__ Ch, u16* __restrict__ Cl,
             long long cBatch, int ldc, int ostride, int nk)
{
    constexpr int NT = SPLIT ? 4 : 2;           // tiles: Ah, Bh, (Al, Bl)
    __shared__ u16 smem[NT * 8192];             // 16KB per tile

    int z = blockIdx.z;
    const u16* Ab  = Ah + (size_t)(aBatch * z) + (size_t)blockIdx.y * 128 * lda;
    const u16* Bb  = Bh + (size_t)(bBatch * z) + (size_t)blockIdx.x * 128 * ldb;

    int tid = threadIdx.x;
    int lane = tid & 63, w = tid >> 6;
    int wm = w & 1, wn = w >> 1;
    int frow = lane & 15, g = lane >> 4;

    // staging: wave w stages rows [w*32, w*32+32), 8 rows per call
    int srow = w * 32 + (lane >> 3);
    int slog = (lane & 7) ^ (lane >> 3);
    const u16* pA  = Ab + (size_t)srow * lda + slog * 8;
    const u16* pB  = Bb + (size_t)srow * ldb + slog * 8;
    const u16* pAl = nullptr; const u16* pBl = nullptr;
    if constexpr (SPLIT){
        pAl = Al + (size_t)(aBatch * z) + (size_t)blockIdx.y * 128 * lda + (size_t)srow * lda + slog * 8;
        pBl = Bl + (size_t)(bBatch * z) + (size_t)blockIdx.x * 128 * ldb + (size_t)srow * ldb + slog * 8;
    }
    u16* ldsA  = smem + w * 2048;
    u16* ldsB  = smem + 8192 + w * 2048;
    u16* ldsAl = smem + 16384 + w * 2048;
    u16* ldsBl = smem + 24576 + w * 2048;

    fx4 acc[4][4] = {};

    for (int kt = 0; kt < nk; ++kt){
#pragma unroll
        for (int c = 0; c < 4; c++){
            size_t ga = (size_t)c * 8 * lda;
            size_t gb = (size_t)c * 8 * ldb;
            gload16(pA + ga, ldsA + c * 512);
            gload16(pB + gb, ldsB + c * 512);
            if constexpr (SPLIT){
                gload16(pAl + ga, ldsAl + c * 512);
                gload16(pBl + gb, ldsBl + c * 512);
            }
        }
        __syncthreads();

#pragma unroll
        for (int s = 0; s < 2; s++){
            int ko = ((g + 4*s) ^ (frow & 7)) * 8;   // swizzled 16B slot within 128B row
            v8s a_h[4], b_h[4];
#pragma unroll
            for (int mi = 0; mi < 4; mi++)
                a_h[mi] = *(const v8s*)(smem + (wm*64 + mi*16 + frow)*64 + ko);
#pragma unroll
            for (int ni = 0; ni < 4; ni++)
                b_h[ni] = *(const v8s*)(smem + 8192 + (wn*64 + ni*16 + frow)*64 + ko);
            if constexpr (SPLIT){
                v8s a_l[4], b_l[4];
#pragma unroll
                for (int mi = 0; mi < 4; mi++)
                    a_l[mi] = *(const v8s*)(smem + 16384 + (wm*64 + mi*16 + frow)*64 + ko);
#pragma unroll
                for (int ni = 0; ni < 4; ni++)
                    b_l[ni] = *(const v8s*)(smem + 24576 + (wn*64 + ni*16 + frow)*64 + ko);
#pragma unroll
                for (int mi = 0; mi < 4; mi++)
#pragma unroll
                    for (int ni = 0; ni < 4; ni++){
                        acc[mi][ni] = __builtin_amdgcn_mfma_f32_16x16x32_bf16(a_h[mi], b_h[ni], acc[mi][ni], 0, 0, 0);
                        acc[mi][ni] = __builtin_amdgcn_mfma_f32_16x16x32_bf16(a_h[mi], b_l[ni], acc[mi][ni], 0, 0, 0);
                        acc[mi][ni] = __builtin_amdgcn_mfma_f32_16x16x32_bf16(a_l[mi], b_h[ni], acc[mi][ni], 0, 0, 0);
                    }
            } else {
#pragma unroll
                for (int mi = 0; mi < 4; mi++)
#pragma unroll
                    for (int ni = 0; ni < 4; ni++)
                        acc[mi][ni] = __builtin_amdgcn_mfma_f32_16x16x32_bf16(a_h[mi], b_h[ni], acc[mi][ni], 0, 0, 0);
            }
        }
        __syncthreads();
        pA += 64; pB += 64;
        if constexpr (SPLIT){ pAl += 64; pBl += 64; }
    }

    // epilogue: C/D frag layout (m89): col = lane&15, row = (lane>>4)*4 + r
    int gcol0 = blockIdx.x * 128 + wn * 64;
    int grow0 = blockIdx.y * 128 + wm * 64;
    int rgrp  = (lane >> 4) * 4;
    if constexpr (EPI == 0 || EPI == 2 || EPI == 3){
        float* Cb = Cf + (size_t)(cBatch * z);
        float* Gb = (EPI == 3) ? Cg + (size_t)(cBatch * z) : nullptr;
#pragma unroll
        for (int mi = 0; mi < 4; mi++)
#pragma unroll
            for (int ni = 0; ni < 4; ni++){
                int col = gcol0 + ni*16 + frow;
#pragma unroll
                for (int r = 0; r < 4; r++){
                    int row = grow0 + mi*16 + rgrp + r;
                    size_t o = ((size_t)row * ldc + col);
                    float a = acc[mi][ni][r];
                    if constexpr (EPI == 0){
                        Cb[o * (size_t)ostride] = a;
                    } else if constexpr (EPI == 2){
                        Cb[o] += a;
                    } else {
                        float c0 = Cb[o];
                        Cb[o] = c0 + a;
                        Gb[o] = a - c0;
                    }
                }
            }
    } else {
        u16* Chb = Ch + (size_t)(cBatch * z);
        u16* Clb = Cl + (size_t)(cBatch * z);
#pragma unroll
        for (int mi = 0; mi < 4; mi++)
#pragma unroll
            for (int ni = 0; ni < 4; ni++){
                int col = gcol0 + ni*16 + frow;
#pragma unroll
                for (int r = 0; r < 4; r++){
                    int row = grow0 + mi*16 + rgrp + r;
                    float v = acc[mi][ni][r];
                    u16 hh = f2bf(v);
                    size_t o = (size_t)row * ldc + col;
                    Chb[o] = hh;
                    Clb[o] = f2bf(v - bf2f(hh));
                }
            }
    }
}

// ---------------------------------------------------------------------------
extern "C" void kernel_launch(void* const* d_in, const int* in_sizes, int n_in,
                              void* d_out, int out_size, void* d_ws, size_t ws_size,
                              hipStream_t stream)
{
    const float* zr   = (const float*)d_in[0];
    const float* zi   = (const float*)d_in[1];
    const float* Wq_r = (const float*)d_in[2];
    const float* Wq_i = (const float*)d_in[3];
    const float* Wk_r = (const float*)d_in[4];
    const float* Wk_i = (const float*)d_in[5];
    const float* Wv_r = (const float*)d_in[6];
    const float* Wv_i = (const float*)d_in[7];

    constexpr long long Bn = 4, S = 2048, DI = 512;
    // ---- workspace layout (peak ~226 MiB, same as prior rounds) ----
    // A: [0, 100663296)          Chi/Clo -> later Wbf
    // B: [100663296, 134217728)  qs/kd hi/lo -> later Vt/Vti
    // C: [134217728, ...)        Z + Wt (proj) -> later bufX (Si)
    char* ws = (char*)d_ws;
    u16* Chi = (u16*)ws;                       // [8192][3072] bf16 hi
    u16* Clo = Chi + 25165824;                 // lo
    u16* qsh = (u16*)(ws + 100663296);         // [8192][512] each
    u16* qsl = qsh + 4194304;
    u16* kdh = qsl + 4194304;
    u16* kdl = kdh + 4194304;
    u16* Vt  = qsh;                            // reuse B after t3: [4][512][2048]
    u16* Vti = qsh + 4194304;
    char* ws2 = ws + 134217728;
    u16* Zh  = (u16*)ws2;                      // [8192][2048]
    u16* Zl  = Zh + 16777216;
    u16* Wth = Zl + 16777216;                  // [3072][2048]
    u16* Wtl = Wth + 6291456;
    float* bufX = (float*)ws2;                 // reuse C after proj: [4][2048][2048]
    u16* Wbf = (u16*)ws;                       // reuse A after vt: [8192][2048]

    long long attn_elems = Bn * S * S;                       // 16777216
    bool interleaved = ((long long)out_size - attn_elems) == 2LL * Bn * S * DI;
    float* outP = (float*)d_out;
    float* attn = outP + ((long long)out_size - attn_elems); // t1/Sr scratch -> weights

    dim3 b256(256);
    convZ_kernel<<<16384, b256, 0, stream>>>(zr, zi, Zh, Zl);
    convW_kernel<<<dim3(64, 96), dim3(32, 8), 0, stream>>>(Wq_r, Wq_i, Wk_r, Wk_i, Wv_r, Wv_i, Wth, Wtl);

    // proj: C[8192][3072] = Z * Wt^T   (split, hi/lo out)
    gemm_bt<1,1><<<dim3(24, 64, 1), b256, 0, stream>>>(
        Zh, Zl, 0, 2048,
        Wth, Wtl, 0, 2048,
        nullptr, nullptr, Chi, Clo, 0, 3072, 1, 2048/64);

    // Karatsuba prep: qs = qr+qi, kd = kr-ki (hi/lo)
    prep_kernel<<<4096, b256, 0, stream>>>(Chi, Clo, qsh, qsl, kdh, kdl);

    // t1 = qr*kr^T -> attn
    gemm_bt<1,0><<<dim3(16, 16, 4), b256, 0, stream>>>(
        Chi, Clo, 2048LL*3072, 3072,
        Chi + 1024, Clo + 1024, 2048LL*3072, 3072,
        attn, nullptr, nullptr, nullptr, 2048LL*2048, 2048, 1, 512/64);

    // t2 = qi*ki^T; attn = t1+t2 (=Sr), bufX = t2-t1
    gemm_bt<1,3><<<dim3(16, 16, 4), b256, 0, stream>>>(
        Chi + 512, Clo + 512, 2048LL*3072, 3072,
        Chi + 1536, Clo + 1536, 2048LL*3072, 3072,
        attn, bufX, nullptr, nullptr, 2048LL*2048, 2048, 1, 512/64);

    // t3 = (qr+qi)*(kr-ki)^T; bufX += t3 (=Si)
    gemm_bt<1,2><<<dim3(16, 16, 4), b256, 0, stream>>>(
        qsh, qsl, 2048LL*512, 512,
        kdh, kdl, 2048LL*512, 512,
        bufX, nullptr, nullptr, nullptr, 2048LL*2048, 2048, 1, 512/64);

    // Vt: vr (cols 2048..2559) transposed per batch (into region B, freed by t3)
    vt_kernel<<<dim3(64, 16, 4), dim3(32, 8), 0, stream>>>(Chi, 2048, Vt);
    if (interleaved)
        vt_kernel<<<dim3(64, 16, 4), dim3(32, 8), 0, stream>>>(Chi, 2560, Vti);

    softmax_kernel<<<8192, b256, 0, stream>>>(attn, bufX, Wbf);

    // PV: out[s][d] = sum_t W[s][t] * vr[t][d]  == Wbf * Vt^T
    if (!interleaved){
        gemm_bt<0,0><<<dim3(4, 16, 4), b256, 0, stream>>>(
            Wbf, nullptr, 2048LL*2048, 2048,
            Vt, nullptr, 512LL*2048, 2048,
            outP, nullptr, nullptr, nullptr, 2048LL*512, 512, 1, 2048/64);
    } else {
        gemm_bt<0,0><<<dim3(4, 16, 4), b256, 0, stream>>>(
            Wbf, nullptr, 2048LL*2048, 2048,
            Vt, nullptr, 512LL*2048, 2048,
            outP, nullptr, nullptr, nullptr, 2048LL*512*2, 512, 2, 2048/64);
        gemm_bt<0,0><<<dim3(4, 16, 4), b256, 0, stream>>>(
            Wbf, nullptr, 2048LL*2048, 2048,
            Vti, nullptr, 512LL*2048, 2048,
            outP + 1, nullptr, nullptr, nullptr, 2048LL*512*2, 512, 2, 2048/64);
    }
    (void)in_sizes; (void)n_in; (void)ws_size;
}

// Round 5
// 671.952 us; speedup vs baseline: 1.0852x; 1.0852x over previous
//
#include <hip/hip_runtime.h>
#include <hip/hip_bf16.h>

typedef unsigned short u16;
typedef u16   u16x4 __attribute__((ext_vector_type(4)));
typedef u16   u16x8 __attribute__((ext_vector_type(8)));
typedef short v8s   __attribute__((ext_vector_type(8)));   // 8 bf16 bits for MFMA A/B
typedef float fx4   __attribute__((ext_vector_type(4)));

#define DEVINL __device__ __forceinline__

DEVINL u16 f2bf(float x){                 // round-to-nearest-even fp32 -> bf16
    unsigned u = __float_as_uint(x);
    u = u + 0x7FFFu + ((u >> 16) & 1u);
    return (u16)(u >> 16);
}
DEVINL float bf2f(u16 h){ return __uint_as_float(((unsigned)h) << 16); }

// async global -> LDS, 16B per lane (dest = wave-uniform base + lane*16)
DEVINL void gload16(const u16* g, u16* l){
    __builtin_amdgcn_global_load_lds(
        (const __attribute__((address_space(1))) void*)g,
        (__attribute__((address_space(3))) void*)l, 16, 0, 0);
}

// ---------------- conversion: z (fp32) -> Z[8192][2048] bf16 hi/lo ---------
__global__ void convZ_kernel(const float* __restrict__ zr, const float* __restrict__ zi,
                             u16* __restrict__ Zh, u16* __restrict__ Zl){
    int idx = blockIdx.x * blockDim.x + threadIdx.x;   // one float4 each
    size_t i4 = (size_t)idx * 4;
    int m = (int)(i4 >> 11);
    int c = (int)(i4 & 2047);
    const float* src = (c < 1024) ? (zr + (size_t)m*1024 + c)
                                  : (zi + (size_t)m*1024 + (c - 1024));
    fx4 v = *(const fx4*)src;
    u16x4 h, l;
#pragma unroll
    for (int j = 0; j < 4; j++){
        u16 hh = f2bf(v[j]); h[j] = hh; l[j] = f2bf(v[j] - bf2f(hh));
    }
    *(u16x4*)(Zh + i4) = h;
    *(u16x4*)(Zl + i4) = l;
}

// ------- conversion: W* (fp32 [1024][512]) -> Wt[3072][2048] bf16 hi/lo -----
__global__ void convW_kernel(const float* __restrict__ Wq_r, const float* __restrict__ Wq_i,
                             const float* __restrict__ Wk_r, const float* __restrict__ Wk_i,
                             const float* __restrict__ Wv_r, const float* __restrict__ Wv_i,
                             u16* __restrict__ Wth, u16* __restrict__ Wtl){
    __shared__ float t[32][33];
    int k0 = blockIdx.x * 32;          // 0..2047
    int c0 = blockIdx.y * 32;          // 0..3071
    int blk = c0 >> 9;  int j0 = c0 & 511;
    int pair = blk >> 1, ri = blk & 1;
    int hh = k0 >> 10;  int ks0 = k0 & 1023;
    const float* Ws[6] = {Wq_r, Wq_i, Wk_r, Wk_i, Wv_r, Wv_i};
    const float* src; float sign = 1.f;
    if (ri == 0){ if (hh == 0) src = Ws[pair*2]; else { src = Ws[pair*2+1]; sign = -1.f; } }
    else        { src = (hh == 0) ? Ws[pair*2+1] : Ws[pair*2]; }
    int tx = threadIdx.x, ty = threadIdx.y;
    for (int yy = ty; yy < 32; yy += 8)
        t[yy][tx] = src[(size_t)(ks0 + yy)*512 + j0 + tx];
    __syncthreads();
    for (int yy = ty; yy < 32; yy += 8){
        float v = sign * t[tx][yy];
        u16 h2 = f2bf(v);
        size_t o = (size_t)(c0 + yy)*2048 + k0 + tx;
        Wth[o] = h2;
        Wtl[o] = f2bf(v - bf2f(h2));
    }
}

// ---------------- Vt[b][d][t] = C[(b*2048+t)*3072 + colOff + d] -------------
__global__ void vt_kernel(const u16* __restrict__ C, int colOff, u16* __restrict__ Vt){
    __shared__ u16 t[32][34];
    int t0 = blockIdx.x * 32; int d0 = blockIdx.y * 32; int b = blockIdx.z;
    int tx = threadIdx.x, ty = threadIdx.y;
    const u16* src = C + (size_t)b*2048*3072 + colOff;
    for (int yy = ty; yy < 32; yy += 8)
        t[yy][tx] = src[(size_t)(t0 + yy)*3072 + d0 + tx];
    __syncthreads();
    u16* dst = Vt + (size_t)b*512*2048;
    for (int yy = ty; yy < 32; yy += 8)
        dst[(size_t)(d0 + yy)*2048 + t0 + tx] = t[tx][yy];
}

// ------ fused hybrid + row softmax (2048 cols), writes fp32 + bf16 ----------
__global__ __launch_bounds__(256)
void softmax_kernel(float* __restrict__ H, const float* __restrict__ SiP, u16* __restrict__ Wbf){
    int row = blockIdx.x;
    float* p = H + (size_t)row * 2048;
    const float* q = SiP + (size_t)row * 2048;
    int tid = threadIdx.x;
    fx4 v[2];
#pragma unroll
    for (int i = 0; i < 2; i++){
        fx4 sr = *(fx4*)(p + i*1024 + tid*4);
        fx4 si = *(const fx4*)(q + i*1024 + tid*4);
#pragma unroll
        for (int j = 0; j < 4; j++){
            float mag = sqrtf(sr[j]*sr[j] + si[j]*si[j]);
            float ph  = sr[j] / fmaxf(mag, 1e-30f);
            v[i][j] = (mag + 0.3f*ph) * 0.044194173824159216f;   // 1/sqrt(512)
        }
    }
    float m = -1e30f;
#pragma unroll
    for (int i = 0; i < 2; i++)
#pragma unroll
        for (int j = 0; j < 4; j++) m = fmaxf(m, v[i][j]);
    for (int k = 1; k < 64; k <<= 1) m = fmaxf(m, __shfl_xor(m, k));
    __shared__ float sm[4], ss[4];
    int w = tid >> 6, lane = tid & 63;
    if (lane == 0) sm[w] = m;
    __syncthreads();
    m = fmaxf(fmaxf(sm[0], sm[1]), fmaxf(sm[2], sm[3]));
    float s = 0.f;
#pragma unroll
    for (int i = 0; i < 2; i++)
#pragma unroll
        for (int j = 0; j < 4; j++){ v[i][j] = __expf(v[i][j] - m); s += v[i][j]; }
    for (int k = 1; k < 64; k <<= 1) s += __shfl_xor(s, k);
    if (lane == 0) ss[w] = s;
    __syncthreads();
    s = ss[0] + ss[1] + ss[2] + ss[3];
    float inv = 1.f / s;
    u16* wb = Wbf + (size_t)row * 2048;
#pragma unroll
    for (int i = 0; i < 2; i++){
        fx4 o; u16x4 ob;
#pragma unroll
        for (int j = 0; j < 4; j++){ o[j] = v[i][j] * inv; ob[j] = f2bf(o[j]); }
        *(fx4*)(p + i*1024 + tid*4) = o;
        *(u16x4*)(wb + i*1024 + tid*4) = ob;
    }
}

// -------- fused dual score GEMM: Sr = qr*kr^T + qi*ki^T, Si = qi*kr^T - qr*ki^T
// q,k slices read directly from C (hi/lo): qr=cols[0,512), qi=[512,1024),
// kr=[1024,1536), ki=[1536,2048). K=512 per product, bf16x3 split each.
// LDS: 8 streams x [128 rows][32 u16] (64B rows, linear, bank-minimal).
__global__ __launch_bounds__(256, 2)
void score2_kernel(const u16* __restrict__ Chi, const u16* __restrict__ Clo,
                   float* __restrict__ Sr, float* __restrict__ Si)
{
    __shared__ u16 smem[8 * 4096];   // 64KB
    int z = blockIdx.z;
    int tid = threadIdx.x, lane = tid & 63, w = tid >> 6;
    int wm = w & 1, wn = w >> 1;
    int frow = lane & 15, g = lane >> 4;

    // staging: per call (1KB/wave) rows w*32+c*16+(lane>>2), 64B row segment
    int srow = w * 32 + (lane >> 2);
    int scol = (lane & 3) * 8;
    size_t qoff = ((size_t)z*2048 + blockIdx.y*128 + srow) * 3072 + scol;
    size_t koff = ((size_t)z*2048 + blockIdx.x*128 + srow) * 3072 + 1024 + scol;
    u16* L = smem;   // stream s at s*4096 u16

    v8s sgn8;
#pragma unroll
    for (int j = 0; j < 8; j++) sgn8[j] = (short)0x8000;

    fx4 aR[4][4] = {}, aI[4][4] = {};

    for (int kt = 0; kt < 16; ++kt){
        int k0 = kt * 32;
#pragma unroll
        for (int c = 0; c < 2; c++){
            size_t q = qoff + (size_t)c * 49152 + k0;   // 16 rows * 3072
            size_t k = koff + (size_t)c * 49152 + k0;
            u16* d = L + w * 1024 + c * 512;
            gload16(Chi + q,       d);             // qr_h
            gload16(Clo + q,       d + 4096);      // qr_l
            gload16(Chi + q + 512, d + 8192);      // qi_h
            gload16(Clo + q + 512, d + 12288);     // qi_l
            gload16(Chi + k,       d + 16384);     // kr_h
            gload16(Clo + k,       d + 20480);     // kr_l
            gload16(Chi + k + 512, d + 24576);     // ki_h
            gload16(Clo + k + 512, d + 28672);     // ki_l
        }
        __syncthreads();

        v8s ar_h[4], ar_l[4], ai_h[4], ai_l[4];
#pragma unroll
        for (int mi = 0; mi < 4; mi++){
            int off = (wm*64 + mi*16 + frow) * 32 + g * 8;
            ar_h[mi] = *(const v8s*)(L + off);
            ar_l[mi] = *(const v8s*)(L + 4096  + off);
            ai_h[mi] = *(const v8s*)(L + 8192  + off);
            ai_l[mi] = *(const v8s*)(L + 12288 + off);
        }
#pragma unroll
        for (int ni = 0; ni < 4; ni++){
            int off = (wn*64 + ni*16 + frow) * 32 + g * 8;
            v8s br_h = *(const v8s*)(L + 16384 + off);
            v8s br_l = *(const v8s*)(L + 20480 + off);
            v8s bi_h = *(const v8s*)(L + 24576 + off);
            v8s bi_l = *(const v8s*)(L + 28672 + off);
            v8s bn_h = bi_h ^ sgn8;
            v8s bn_l = bi_l ^ sgn8;
#pragma unroll
            for (int mi = 0; mi < 4; mi++){
                // Sr += qr*kr + qi*ki   (bf16x3 each)
                aR[mi][ni] = __builtin_amdgcn_mfma_f32_16x16x32_bf16(ar_h[mi], br_h, aR[mi][ni], 0, 0, 0);
                aR[mi][ni] = __builtin_amdgcn_mfma_f32_16x16x32_bf16(ar_h[mi], br_l, aR[mi][ni], 0, 0, 0);
                aR[mi][ni] = __builtin_amdgcn_mfma_f32_16x16x32_bf16(ar_l[mi], br_h, aR[mi][ni], 0, 0, 0);
                aR[mi][ni] = __builtin_amdgcn_mfma_f32_16x16x32_bf16(ai_h[mi], bi_h, aR[mi][ni], 0, 0, 0);
                aR[mi][ni] = __builtin_amdgcn_mfma_f32_16x16x32_bf16(ai_h[mi], bi_l, aR[mi][ni], 0, 0, 0);
                aR[mi][ni] = __builtin_amdgcn_mfma_f32_16x16x32_bf16(ai_l[mi], bi_h, aR[mi][ni], 0, 0, 0);
                // Si += qi*kr + qr*(-ki)
                aI[mi][ni] = __builtin_amdgcn_mfma_f32_16x16x32_bf16(ai_h[mi], br_h, aI[mi][ni], 0, 0, 0);
                aI[mi][ni] = __builtin_amdgcn_mfma_f32_16x16x32_bf16(ai_h[mi], br_l, aI[mi][ni], 0, 0, 0);
                aI[mi][ni] = __builtin_amdgcn_mfma_f32_16x16x32_bf16(ai_l[mi], br_h, aI[mi][ni], 0, 0, 0);
                aI[mi][ni] = __builtin_amdgcn_mfma_f32_16x16x32_bf16(ar_h[mi], bn_h, aI[mi][ni], 0, 0, 0);
                aI[mi][ni] = __builtin_amdgcn_mfma_f32_16x16x32_bf16(ar_h[mi], bn_l, aI[mi][ni], 0, 0, 0);
                aI[mi][ni] = __builtin_amdgcn_mfma_f32_16x16x32_bf16(ar_l[mi], bn_h, aI[mi][ni], 0, 0, 0);
            }
        }
        __syncthreads();
    }

    // epilogue: col = lane&15, row = (lane>>4)*4 + r (m89 layout)
    size_t cb = (size_t)z * 2048 * 2048;
    int gcol0 = blockIdx.x * 128 + wn * 64;
    int grow0 = blockIdx.y * 128 + wm * 64;
    int rgrp  = (lane >> 4) * 4;
#pragma unroll
    for (int mi = 0; mi < 4; mi++)
#pragma unroll
        for (int ni = 0; ni < 4; ni++){
            int col = gcol0 + ni*16 + frow;
#pragma unroll
            for (int r = 0; r < 4; r++){
                size_t o = cb + (size_t)(grow0 + mi*16 + rgrp + r) * 2048 + col;
                Sr[o] = aR[mi][ni][r];
                Si[o] = aI[mi][ni][r];
            }
        }
}

// ---------------- GEMM: C = A * B^T (bf16 MFMA, optional hi/lo split) -------
// BK=64; LDS tiles [128 rows][64 u16], XOR-swizzled (phys slot = log slot ^ (row&7)).
// SPLIT=1: C ~= Ah*Bh + Ah*Bl + Al*Bh   EPI=0: fp32 out (stride)  EPI=1: hi/lo bf16
template<int SPLIT, int EPI>
__global__ __launch_bounds__(256, 2)
void gemm_bt(const u16* __restrict__ Ah, const u16* __restrict__ Al,
             long long aBatch, int lda,
             const u16* __restrict__ Bh, const u16* __restrict__ Bl,
             long long bBatch, int ldb,
             float* __restrict__ Cf, u16* __restrict__ Ch, u16* __restrict__ Cl,
             long long cBatch, int ldc, int ostride, int nk)
{
    constexpr int NT = SPLIT ? 4 : 2;
    __shared__ u16 smem[NT * 8192];

    int z = blockIdx.z;
    const u16* Ab  = Ah + (size_t)(aBatch * z) + (size_t)blockIdx.y * 128 * lda;
    const u16* Bb  = Bh + (size_t)(bBatch * z) + (size_t)blockIdx.x * 128 * ldb;

    int tid = threadIdx.x;
    int lane = tid & 63, w = tid >> 6;
    int wm = w & 1, wn = w >> 1;
    int frow = lane & 15, g = lane >> 4;

    int srow = w * 32 + (lane >> 3);
    int slog = (lane & 7) ^ (lane >> 3);
    const u16* pA  = Ab + (size_t)srow * lda + slog * 8;
    const u16* pB  = Bb + (size_t)srow * ldb + slog * 8;
    const u16* pAl = nullptr; const u16* pBl = nullptr;
    if constexpr (SPLIT){
        pAl = Al + (size_t)(aBatch * z) + (size_t)blockIdx.y * 128 * lda + (size_t)srow * lda + slog * 8;
        pBl = Bl + (size_t)(bBatch * z) + (size_t)blockIdx.x * 128 * ldb + (size_t)srow * ldb + slog * 8;
    }
    u16* ldsA  = smem + w * 2048;
    u16* ldsB  = smem + 8192 + w * 2048;
    u16* ldsAl = smem + 16384 + w * 2048;
    u16* ldsBl = smem + 24576 + w * 2048;

    fx4 acc[4][4] = {};

    for (int kt = 0; kt < nk; ++kt){
#pragma unroll
        for (int c = 0; c < 4; c++){
            size_t ga = (size_t)c * 8 * lda;
            size_t gb = (size_t)c * 8 * ldb;
            gload16(pA + ga, ldsA + c * 512);
            gload16(pB + gb, ldsB + c * 512);
            if constexpr (SPLIT){
                gload16(pAl + ga, ldsAl + c * 512);
                gload16(pBl + gb, ldsBl + c * 512);
            }
        }
        __syncthreads();

#pragma unroll
        for (int s = 0; s < 2; s++){
            int ko = ((g + 4*s) ^ (frow & 7)) * 8;
            v8s a_h[4], b_h[4];
#pragma unroll
            for (int mi = 0; mi < 4; mi++)
                a_h[mi] = *(const v8s*)(smem + (wm*64 + mi*16 + frow)*64 + ko);
#pragma unroll
            for (int ni = 0; ni < 4; ni++)
                b_h[ni] = *(const v8s*)(smem + 8192 + (wn*64 + ni*16 + frow)*64 + ko);
            if constexpr (SPLIT){
                v8s a_l[4], b_l[4];
#pragma unroll
                for (int mi = 0; mi < 4; mi++)
                    a_l[mi] = *(const v8s*)(smem + 16384 + (wm*64 + mi*16 + frow)*64 + ko);
#pragma unroll
                for (int ni = 0; ni < 4; ni++)
                    b_l[ni] = *(const v8s*)(smem + 24576 + (wn*64 + ni*16 + frow)*64 + ko);
#pragma unroll
                for (int mi = 0; mi < 4; mi++)
#pragma unroll
                    for (int ni = 0; ni < 4; ni++){
                        acc[mi][ni] = __builtin_amdgcn_mfma_f32_16x16x32_bf16(a_h[mi], b_h[ni], acc[mi][ni], 0, 0, 0);
                        acc[mi][ni] = __builtin_amdgcn_mfma_f32_16x16x32_bf16(a_h[mi], b_l[ni], acc[mi][ni], 0, 0, 0);
                        acc[mi][ni] = __builtin_amdgcn_mfma_f32_16x16x32_bf16(a_l[mi], b_h[ni], acc[mi][ni], 0, 0, 0);
                    }
            } else {
#pragma unroll
                for (int mi = 0; mi < 4; mi++)
#pragma unroll
                    for (int ni = 0; ni < 4; ni++)
                        acc[mi][ni] = __builtin_amdgcn_mfma_f32_16x16x32_bf16(a_h[mi], b_h[ni], acc[mi][ni], 0, 0, 0);
            }
        }
        __syncthreads();
        pA += 64; pB += 64;
        if constexpr (SPLIT){ pAl += 64; pBl += 64; }
    }

    int gcol0 = blockIdx.x * 128 + wn * 64;
    int grow0 = blockIdx.y * 128 + wm * 64;
    int rgrp  = (lane >> 4) * 4;
    if constexpr (EPI == 0){
        float* Cb = Cf + (size_t)(cBatch * z);
#pragma unroll
        for (int mi = 0; mi < 4; mi++)
#pragma unroll
            for (int ni = 0; ni < 4; ni++){
                int col = gcol0 + ni*16 + frow;
#pragma unroll
                for (int r = 0; r < 4; r++){
                    int row = grow0 + mi*16 + rgrp + r;
                    Cb[((size_t)row * ldc + col) * (size_t)ostride] = acc[mi][ni][r];
                }
            }
    } else {
        u16* Chb = Ch + (size_t)(cBatch * z);
        u16* Clb = Cl + (size_t)(cBatch * z);
#pragma unroll
        for (int mi = 0; mi < 4; mi++)
#pragma unroll
            for (int ni = 0; ni < 4; ni++){
                int col = gcol0 + ni*16 + frow;
#pragma unroll
                for (int r = 0; r < 4; r++){
                    int row = grow0 + mi*16 + rgrp + r;
                    float v = acc[mi][ni][r];
                    u16 hh = f2bf(v);
                    size_t o = (size_t)row * ldc + col;
                    Chb[o] = hh;
                    Clb[o] = f2bf(v - bf2f(hh));
                }
            }
    }
}

// ---------------------------------------------------------------------------
extern "C" void kernel_launch(void* const* d_in, const int* in_sizes, int n_in,
                              void* d_out, int out_size, void* d_ws, size_t ws_size,
                              hipStream_t stream)
{
    const float* zr   = (const float*)d_in[0];
    const float* zi   = (const float*)d_in[1];
    const float* Wq_r = (const float*)d_in[2];
    const float* Wq_i = (const float*)d_in[3];
    const float* Wk_r = (const float*)d_in[4];
    const float* Wk_i = (const float*)d_in[5];
    const float* Wv_r = (const float*)d_in[6];
    const float* Wv_i = (const float*)d_in[7];

    constexpr long long Bn = 4, S = 2048, DI = 512;
    // ---- workspace layout (peak ~216 MiB, proven fits) ----
    char* ws = (char*)d_ws;
    u16* Chi = (u16*)ws;                       // [8192][3072] bf16 hi
    u16* Clo = Chi + 25165824;                 // lo
    char* ws2 = ws + 134217728;                // Z/Wt region; reused later
    u16* Zh  = (u16*)ws2;                      // [8192][2048]
    u16* Zl  = Zh + 16777216;
    u16* Wth = Zl + 16777216;                  // [3072][2048]
    u16* Wtl = Wth + 6291456;
    float* bufX = (float*)ws2;                 // reuse Z region after proj: Si [4][2048][2048]
    u16* Vt  = (u16*)(ws2 + 67108864);         // reuse Wt region: [4][512][2048]
    u16* Vti = Vt + 4194304;
    u16* Wbf = (u16*)ws;                       // reuse C region after scores+Vt: [8192][2048]

    long long attn_elems = Bn * S * S;                       // 16777216
    bool interleaved = ((long long)out_size - attn_elems) == 2LL * Bn * S * DI;
    float* outP = (float*)d_out;
    float* attn = outP + ((long long)out_size - attn_elems); // Sr scratch -> weights

    dim3 b256(256);
    convZ_kernel<<<16384, b256, 0, stream>>>(zr, zi, Zh, Zl);
    convW_kernel<<<dim3(64, 96), dim3(32, 8), 0, stream>>>(Wq_r, Wq_i, Wk_r, Wk_i, Wv_r, Wv_i, Wth, Wtl);

    // proj: C[8192][3072] = Z * Wt^T   (split, hi/lo out)
    gemm_bt<1,1><<<dim3(24, 64, 1), b256, 0, stream>>>(
        Zh, Zl, 0, 2048,
        Wth, Wtl, 0, 2048,
        nullptr, Chi, Clo, 0, 3072, 1, 2048/64);

    // fused dual score: Sr -> attn, Si -> bufX
    score2_kernel<<<dim3(16, 16, 4), b256, 0, stream>>>(Chi, Clo, attn, bufX);

    // Vt: vr (cols 2048..2559) transposed per batch
    vt_kernel<<<dim3(64, 16, 4), dim3(32, 8), 0, stream>>>(Chi, 2048, Vt);
    if (interleaved)
        vt_kernel<<<dim3(64, 16, 4), dim3(32, 8), 0, stream>>>(Chi, 2560, Vti);

    softmax_kernel<<<8192, b256, 0, stream>>>(attn, bufX, Wbf);

    // PV: out[s][d] = sum_t W[s][t] * vr[t][d]  == Wbf * Vt^T
    if (!interleaved){
        gemm_bt<0,0><<<dim3(4, 16, 4), b256, 0, stream>>>(
            Wbf, nullptr, 2048LL*2048, 2048,
            Vt, nullptr, 512LL*2048, 2048,
            outP, nullptr, nullptr, 2048LL*512, 512, 1, 2048/64);
    } else {
        gemm_bt<0,0><<<dim3(4, 16, 4), b256, 0, stream>>>(
            Wbf, nullptr, 2048LL*2048, 2048,
            Vt, nullptr, 512LL*2048, 2048,
            outP, nullptr, nullptr, 2048LL*512*2, 512, 2, 2048/64);
        gemm_bt<0,0><<<dim3(4, 16, 4), b256, 0, stream>>>(
            Wbf, nullptr, 2048LL*2048, 2048,
            Vti, nullptr, 512LL*2048, 2048,
            outP + 1, nullptr, nullptr, 2048LL*512*2, 512, 2, 2048/64);
    }
    (void)in_sizes; (void)n_in; (void)ws_size;
}

// Round 6
// 643.682 us; speedup vs baseline: 1.1329x; 1.0439x over previous
//
#include <hip/hip_runtime.h>
#include <hip/hip_bf16.h>

typedef unsigned short u16;
typedef u16   u16x4 __attribute__((ext_vector_type(4)));
typedef u16   u16x8 __attribute__((ext_vector_type(8)));
typedef short v8s   __attribute__((ext_vector_type(8)));   // 8 bf16 bits for MFMA A/B
typedef float fx4   __attribute__((ext_vector_type(4)));

#define DEVINL __device__ __forceinline__

DEVINL u16 f2bf(float x){                 // round-to-nearest-even fp32 -> bf16
    unsigned u = __float_as_uint(x);
    u = u + 0x7FFFu + ((u >> 16) & 1u);
    return (u16)(u >> 16);
}
DEVINL float bf2f(u16 h){ return __uint_as_float(((unsigned)h) << 16); }

// async global -> LDS, 16B per lane (dest = wave-uniform base + lane*16)
DEVINL void gload16(const u16* g, u16* l){
    __builtin_amdgcn_global_load_lds(
        (const __attribute__((address_space(1))) void*)g,
        (__attribute__((address_space(3))) void*)l, 16, 0, 0);
}

// ---------------- conversion: z (fp32) -> Z[8192][2048] bf16 hi/lo ---------
__global__ void convZ_kernel(const float* __restrict__ zr, const float* __restrict__ zi,
                             u16* __restrict__ Zh, u16* __restrict__ Zl){
    int idx = blockIdx.x * blockDim.x + threadIdx.x;   // one float4 each
    size_t i4 = (size_t)idx * 4;
    int m = (int)(i4 >> 11);
    int c = (int)(i4 & 2047);
    const float* src = (c < 1024) ? (zr + (size_t)m*1024 + c)
                                  : (zi + (size_t)m*1024 + (c - 1024));
    fx4 v = *(const fx4*)src;
    u16x4 h, l;
#pragma unroll
    for (int j = 0; j < 4; j++){
        u16 hh = f2bf(v[j]); h[j] = hh; l[j] = f2bf(v[j] - bf2f(hh));
    }
    *(u16x4*)(Zh + i4) = h;
    *(u16x4*)(Zl + i4) = l;
}

// ------- conversion: W* (fp32 [1024][512]) -> Wt[3072][2048] bf16 hi/lo -----
__global__ void convW_kernel(const float* __restrict__ Wq_r, const float* __restrict__ Wq_i,
                             const float* __restrict__ Wk_r, const float* __restrict__ Wk_i,
                             const float* __restrict__ Wv_r, const float* __restrict__ Wv_i,
                             u16* __restrict__ Wth, u16* __restrict__ Wtl){
    __shared__ float t[32][33];
    int k0 = blockIdx.x * 32;          // 0..2047
    int c0 = blockIdx.y * 32;          // 0..3071
    int blk = c0 >> 9;  int j0 = c0 & 511;
    int pair = blk >> 1, ri = blk & 1;
    int hh = k0 >> 10;  int ks0 = k0 & 1023;
    const float* Ws[6] = {Wq_r, Wq_i, Wk_r, Wk_i, Wv_r, Wv_i};
    const float* src; float sign = 1.f;
    if (ri == 0){ if (hh == 0) src = Ws[pair*2]; else { src = Ws[pair*2+1]; sign = -1.f; } }
    else        { src = (hh == 0) ? Ws[pair*2+1] : Ws[pair*2]; }
    int tx = threadIdx.x, ty = threadIdx.y;
    for (int yy = ty; yy < 32; yy += 8)
        t[yy][tx] = src[(size_t)(ks0 + yy)*512 + j0 + tx];
    __syncthreads();
    for (int yy = ty; yy < 32; yy += 8){
        float v = sign * t[tx][yy];
        u16 h2 = f2bf(v);
        size_t o = (size_t)(c0 + yy)*2048 + k0 + tx;
        Wth[o] = h2;
        Wtl[o] = f2bf(v - bf2f(h2));
    }
}

// ---------------- Vt[b][d][t] = C[(b*2048+t)*3072 + colOff + d] -------------
__global__ void vt_kernel(const u16* __restrict__ C, int colOff, u16* __restrict__ Vt){
    __shared__ u16 t[32][34];
    int t0 = blockIdx.x * 32; int d0 = blockIdx.y * 32; int b = blockIdx.z;
    int tx = threadIdx.x, ty = threadIdx.y;
    const u16* src = C + (size_t)b*2048*3072 + colOff;
    for (int yy = ty; yy < 32; yy += 8)
        t[yy][tx] = src[(size_t)(t0 + yy)*3072 + d0 + tx];
    __syncthreads();
    u16* dst = Vt + (size_t)b*512*2048;
    for (int yy = ty; yy < 32; yy += 8)
        dst[(size_t)(d0 + yy)*2048 + t0 + tx] = t[tx][yy];
}

// ------ row softmax (2048 cols) on pre-computed hybrid scores ---------------
__global__ __launch_bounds__(256)
void softmax_kernel(float* __restrict__ H, u16* __restrict__ Wbf){
    int row = blockIdx.x;
    float* p = H + (size_t)row * 2048;
    int tid = threadIdx.x;
    fx4 v[2];
    v[0] = *(fx4*)(p + tid*4);
    v[1] = *(fx4*)(p + 1024 + tid*4);
    float m = -1e30f;
#pragma unroll
    for (int i = 0; i < 2; i++)
#pragma unroll
        for (int j = 0; j < 4; j++) m = fmaxf(m, v[i][j]);
    for (int k = 1; k < 64; k <<= 1) m = fmaxf(m, __shfl_xor(m, k));
    __shared__ float sm[4], ss[4];
    int w = tid >> 6, lane = tid & 63;
    if (lane == 0) sm[w] = m;
    __syncthreads();
    m = fmaxf(fmaxf(sm[0], sm[1]), fmaxf(sm[2], sm[3]));
    float s = 0.f;
#pragma unroll
    for (int i = 0; i < 2; i++)
#pragma unroll
        for (int j = 0; j < 4; j++){ v[i][j] = __expf(v[i][j] - m); s += v[i][j]; }
    for (int k = 1; k < 64; k <<= 1) s += __shfl_xor(s, k);
    if (lane == 0) ss[w] = s;
    __syncthreads();
    s = ss[0] + ss[1] + ss[2] + ss[3];
    float inv = 1.f / s;
    u16* wb = Wbf + (size_t)row * 2048;
#pragma unroll
    for (int i = 0; i < 2; i++){
        fx4 o; u16x4 ob;
#pragma unroll
        for (int j = 0; j < 4; j++){ o[j] = v[i][j] * inv; ob[j] = f2bf(o[j]); }
        *(fx4*)(p + i*1024 + tid*4) = o;
        *(u16x4*)(wb + i*1024 + tid*4) = ob;
    }
}

// -------- fused dual score GEMM + hybrid epilogue ---------------------------
// Sr = qr*kr^T + qi*ki^T, Si = qi*kr^T - qr*ki^T  (bf16x3 each, K=512)
// writes y = (|s| + 0.3*Re/|s|)/sqrt(512) only.
// LDS: 8 streams x [128 rows][32 u16] (64B rows, linear, bank-minimal).
__global__ __launch_bounds__(256, 2)
void score2_kernel(const u16* __restrict__ Chi, const u16* __restrict__ Clo,
                   float* __restrict__ Y)
{
    __shared__ u16 smem[8 * 4096];   // 64KB
    int z = blockIdx.z;
    int tid = threadIdx.x, lane = tid & 63, w = tid >> 6;
    int wm = w & 1, wn = w >> 1;
    int frow = lane & 15, g = lane >> 4;

    int srow = w * 32 + (lane >> 2);
    int scol = (lane & 3) * 8;
    size_t qoff = ((size_t)z*2048 + blockIdx.y*128 + srow) * 3072 + scol;
    size_t koff = ((size_t)z*2048 + blockIdx.x*128 + srow) * 3072 + 1024 + scol;
    u16* L = smem;   // stream s at s*4096 u16

    v8s sgn8;
#pragma unroll
    for (int j = 0; j < 8; j++) sgn8[j] = (short)0x8000;

    fx4 aR[4][4] = {}, aI[4][4] = {};

    for (int kt = 0; kt < 16; ++kt){
        int k0 = kt * 32;
#pragma unroll
        for (int c = 0; c < 2; c++){
            size_t q = qoff + (size_t)c * 49152 + k0;   // 16 rows * 3072
            size_t k = koff + (size_t)c * 49152 + k0;
            u16* d = L + w * 1024 + c * 512;
            gload16(Chi + q,       d);             // qr_h
            gload16(Clo + q,       d + 4096);      // qr_l
            gload16(Chi + q + 512, d + 8192);      // qi_h
            gload16(Clo + q + 512, d + 12288);     // qi_l
            gload16(Chi + k,       d + 16384);     // kr_h
            gload16(Clo + k,       d + 20480);     // kr_l
            gload16(Chi + k + 512, d + 24576);     // ki_h
            gload16(Clo + k + 512, d + 28672);     // ki_l
        }
        __syncthreads();

        v8s ar_h[4], ar_l[4], ai_h[4], ai_l[4];
#pragma unroll
        for (int mi = 0; mi < 4; mi++){
            int off = (wm*64 + mi*16 + frow) * 32 + g * 8;
            ar_h[mi] = *(const v8s*)(L + off);
            ar_l[mi] = *(const v8s*)(L + 4096  + off);
            ai_h[mi] = *(const v8s*)(L + 8192  + off);
            ai_l[mi] = *(const v8s*)(L + 12288 + off);
        }
#pragma unroll
        for (int ni = 0; ni < 4; ni++){
            int off = (wn*64 + ni*16 + frow) * 32 + g * 8;
            v8s br_h = *(const v8s*)(L + 16384 + off);
            v8s br_l = *(const v8s*)(L + 20480 + off);
            v8s bi_h = *(const v8s*)(L + 24576 + off);
            v8s bi_l = *(const v8s*)(L + 28672 + off);
            v8s bn_h = bi_h ^ sgn8;
            v8s bn_l = bi_l ^ sgn8;
#pragma unroll
            for (int mi = 0; mi < 4; mi++){
                aR[mi][ni] = __builtin_amdgcn_mfma_f32_16x16x32_bf16(ar_h[mi], br_h, aR[mi][ni], 0, 0, 0);
                aR[mi][ni] = __builtin_amdgcn_mfma_f32_16x16x32_bf16(ar_h[mi], br_l, aR[mi][ni], 0, 0, 0);
                aR[mi][ni] = __builtin_amdgcn_mfma_f32_16x16x32_bf16(ar_l[mi], br_h, aR[mi][ni], 0, 0, 0);
                aR[mi][ni] = __builtin_amdgcn_mfma_f32_16x16x32_bf16(ai_h[mi], bi_h, aR[mi][ni], 0, 0, 0);
                aR[mi][ni] = __builtin_amdgcn_mfma_f32_16x16x32_bf16(ai_h[mi], bi_l, aR[mi][ni], 0, 0, 0);
                aR[mi][ni] = __builtin_amdgcn_mfma_f32_16x16x32_bf16(ai_l[mi], bi_h, aR[mi][ni], 0, 0, 0);
                aI[mi][ni] = __builtin_amdgcn_mfma_f32_16x16x32_bf16(ai_h[mi], br_h, aI[mi][ni], 0, 0, 0);
                aI[mi][ni] = __builtin_amdgcn_mfma_f32_16x16x32_bf16(ai_h[mi], br_l, aI[mi][ni], 0, 0, 0);
                aI[mi][ni] = __builtin_amdgcn_mfma_f32_16x16x32_bf16(ai_l[mi], br_h, aI[mi][ni], 0, 0, 0);
                aI[mi][ni] = __builtin_amdgcn_mfma_f32_16x16x32_bf16(ar_h[mi], bn_h, aI[mi][ni], 0, 0, 0);
                aI[mi][ni] = __builtin_amdgcn_mfma_f32_16x16x32_bf16(ar_h[mi], bn_l, aI[mi][ni], 0, 0, 0);
                aI[mi][ni] = __builtin_amdgcn_mfma_f32_16x16x32_bf16(ar_l[mi], bn_h, aI[mi][ni], 0, 0, 0);
            }
        }
        __syncthreads();
    }

    // epilogue: hybrid transform in-register, single write
    size_t cb = (size_t)z * 2048 * 2048;
    int gcol0 = blockIdx.x * 128 + wn * 64;
    int grow0 = blockIdx.y * 128 + wm * 64;
    int rgrp  = (lane >> 4) * 4;
#pragma unroll
    for (int mi = 0; mi < 4; mi++)
#pragma unroll
        for (int ni = 0; ni < 4; ni++){
            int col = gcol0 + ni*16 + frow;
#pragma unroll
            for (int r = 0; r < 4; r++){
                size_t o = cb + (size_t)(grow0 + mi*16 + rgrp + r) * 2048 + col;
                float re = aR[mi][ni][r], im = aI[mi][ni][r];
                float mag = sqrtf(re*re + im*im);
                float ph  = re / fmaxf(mag, 1e-30f);
                Y[o] = (mag + 0.3f*ph) * 0.044194173824159216f;   // 1/sqrt(512)
            }
        }
}

// ---------------- GEMM: C = A * B^T (bf16 MFMA, optional hi/lo split) -------
// BK=64; LDS tiles [128 rows][64 u16], XOR-swizzled (phys slot = log slot ^ (row&7)).
// SPLIT=1: C ~= Ah*Bh + Ah*Bl + Al*Bh
// EPI=0: fp32 out (stride)  EPI=1: hi/lo bf16  EPI=4: bf16 hi only
template<int SPLIT, int EPI>
__global__ __launch_bounds__(256, 2)
void gemm_bt(const u16* __restrict__ Ah, const u16* __restrict__ Al,
             long long aBatch, int lda,
             const u16* __restrict__ Bh, const u16* __restrict__ Bl,
             long long bBatch, int ldb,
             float* __restrict__ Cf, u16* __restrict__ Ch, u16* __restrict__ Cl,
             long long cBatch, int ldc, int ostride, int nk)
{
    constexpr int NT = SPLIT ? 4 : 2;
    __shared__ u16 smem[NT * 8192];

    int z = blockIdx.z;
    const u16* Ab  = Ah + (size_t)(aBatch * z) + (size_t)blockIdx.y * 128 * lda;
    const u16* Bb  = Bh + (size_t)(bBatch * z) + (size_t)blockIdx.x * 128 * ldb;

    int tid = threadIdx.x;
    int lane = tid & 63, w = tid >> 6;
    int wm = w & 1, wn = w >> 1;
    int frow = lane & 15, g = lane >> 4;

    int srow = w * 32 + (lane >> 3);
    int slog = (lane & 7) ^ (lane >> 3);
    const u16* pA  = Ab + (size_t)srow * lda + slog * 8;
    const u16* pB  = Bb + (size_t)srow * ldb + slog * 8;
    const u16* pAl = nullptr; const u16* pBl = nullptr;
    if constexpr (SPLIT){
        pAl = Al + (size_t)(aBatch * z) + (size_t)blockIdx.y * 128 * lda + (size_t)srow * lda + slog * 8;
        pBl = Bl + (size_t)(bBatch * z) + (size_t)blockIdx.x * 128 * ldb + (size_t)srow * ldb + slog * 8;
    }
    u16* ldsA  = smem + w * 2048;
    u16* ldsB  = smem + 8192 + w * 2048;
    u16* ldsAl = smem + 16384 + w * 2048;
    u16* ldsBl = smem + 24576 + w * 2048;

    fx4 acc[4][4] = {};

    for (int kt = 0; kt < nk; ++kt){
#pragma unroll
        for (int c = 0; c < 4; c++){
            size_t ga = (size_t)c * 8 * lda;
            size_t gb = (size_t)c * 8 * ldb;
            gload16(pA + ga, ldsA + c * 512);
            gload16(pB + gb, ldsB + c * 512);
            if constexpr (SPLIT){
                gload16(pAl + ga, ldsAl + c * 512);
                gload16(pBl + gb, ldsBl + c * 512);
            }
        }
        __syncthreads();

#pragma unroll
        for (int s = 0; s < 2; s++){
            int ko = ((g + 4*s) ^ (frow & 7)) * 8;
            v8s a_h[4], b_h[4];
#pragma unroll
            for (int mi = 0; mi < 4; mi++)
                a_h[mi] = *(const v8s*)(smem + (wm*64 + mi*16 + frow)*64 + ko);
#pragma unroll
            for (int ni = 0; ni < 4; ni++)
                b_h[ni] = *(const v8s*)(smem + 8192 + (wn*64 + ni*16 + frow)*64 + ko);
            if constexpr (SPLIT){
                v8s a_l[4], b_l[4];
#pragma unroll
                for (int mi = 0; mi < 4; mi++)
                    a_l[mi] = *(const v8s*)(smem + 16384 + (wm*64 + mi*16 + frow)*64 + ko);
#pragma unroll
                for (int ni = 0; ni < 4; ni++)
                    b_l[ni] = *(const v8s*)(smem + 24576 + (wn*64 + ni*16 + frow)*64 + ko);
#pragma unroll
                for (int mi = 0; mi < 4; mi++)
#pragma unroll
                    for (int ni = 0; ni < 4; ni++){
                        acc[mi][ni] = __builtin_amdgcn_mfma_f32_16x16x32_bf16(a_h[mi], b_h[ni], acc[mi][ni], 0, 0, 0);
                        acc[mi][ni] = __builtin_amdgcn_mfma_f32_16x16x32_bf16(a_h[mi], b_l[ni], acc[mi][ni], 0, 0, 0);
                        acc[mi][ni] = __builtin_amdgcn_mfma_f32_16x16x32_bf16(a_l[mi], b_h[ni], acc[mi][ni], 0, 0, 0);
                    }
            } else {
#pragma unroll
                for (int mi = 0; mi < 4; mi++)
#pragma unroll
                    for (int ni = 0; ni < 4; ni++)
                        acc[mi][ni] = __builtin_amdgcn_mfma_f32_16x16x32_bf16(a_h[mi], b_h[ni], acc[mi][ni], 0, 0, 0);
            }
        }
        __syncthreads();
        pA += 64; pB += 64;
        if constexpr (SPLIT){ pAl += 64; pBl += 64; }
    }

    int gcol0 = blockIdx.x * 128 + wn * 64;
    int grow0 = blockIdx.y * 128 + wm * 64;
    int rgrp  = (lane >> 4) * 4;
    if constexpr (EPI == 0){
        float* Cb = Cf + (size_t)(cBatch * z);
#pragma unroll
        for (int mi = 0; mi < 4; mi++)
#pragma unroll
            for (int ni = 0; ni < 4; ni++){
                int col = gcol0 + ni*16 + frow;
#pragma unroll
                for (int r = 0; r < 4; r++){
                    int row = grow0 + mi*16 + rgrp + r;
                    Cb[((size_t)row * ldc + col) * (size_t)ostride] = acc[mi][ni][r];
                }
            }
    } else if constexpr (EPI == 1){
        u16* Chb = Ch + (size_t)(cBatch * z);
        u16* Clb = Cl + (size_t)(cBatch * z);
#pragma unroll
        for (int mi = 0; mi < 4; mi++)
#pragma unroll
            for (int ni = 0; ni < 4; ni++){
                int col = gcol0 + ni*16 + frow;
#pragma unroll
                for (int r = 0; r < 4; r++){
                    int row = grow0 + mi*16 + rgrp + r;
                    float v = acc[mi][ni][r];
                    u16 hh = f2bf(v);
                    size_t o = (size_t)row * ldc + col;
                    Chb[o] = hh;
                    Clb[o] = f2bf(v - bf2f(hh));
                }
            }
    } else {   // EPI == 4: bf16 hi only
        u16* Chb = Ch + (size_t)(cBatch * z);
#pragma unroll
        for (int mi = 0; mi < 4; mi++)
#pragma unroll
            for (int ni = 0; ni < 4; ni++){
                int col = gcol0 + ni*16 + frow;
#pragma unroll
                for (int r = 0; r < 4; r++){
                    int row = grow0 + mi*16 + rgrp + r;
                    Chb[(size_t)row * ldc + col] = f2bf(acc[mi][ni][r]);
                }
            }
    }
}

// ---------------------------------------------------------------------------
extern "C" void kernel_launch(void* const* d_in, const int* in_sizes, int n_in,
                              void* d_out, int out_size, void* d_ws, size_t ws_size,
                              hipStream_t stream)
{
    const float* zr   = (const float*)d_in[0];
    const float* zi   = (const float*)d_in[1];
    const float* Wq_r = (const float*)d_in[2];
    const float* Wq_i = (const float*)d_in[3];
    const float* Wk_r = (const float*)d_in[4];
    const float* Wk_i = (const float*)d_in[5];
    const float* Wv_r = (const float*)d_in[6];
    const float* Wv_i = (const float*)d_in[7];

    constexpr long long Bn = 4, S = 2048, DI = 512;
    // ---- workspace layout (peak ~216 MiB, proven fits) ----
    char* ws = (char*)d_ws;
    u16* Chi = (u16*)ws;                       // [8192][3072] bf16 hi
    u16* Clo = Chi + 25165824;                 // lo
    char* ws2 = ws + 134217728;                // Z/Wt region; Vt reuses Wt after proj
    u16* Zh  = (u16*)ws2;                      // [8192][2048]
    u16* Zl  = Zh + 16777216;
    u16* Wth = Zl + 16777216;                  // [3072][2048]
    u16* Wtl = Wth + 6291456;
    u16* Vt  = (u16*)(ws2 + 67108864);         // reuse Wt region: [4][512][2048]
    u16* Vti = Vt + 4194304;
    u16* Wbf = (u16*)ws;                       // reuse C region after scores+Vt: [8192][2048]

    long long attn_elems = Bn * S * S;                       // 16777216
    bool interleaved = ((long long)out_size - attn_elems) == 2LL * Bn * S * DI;
    float* outP = (float*)d_out;
    float* attn = outP + ((long long)out_size - attn_elems); // y scratch -> weights

    dim3 b256(256);
    convZ_kernel<<<16384, b256, 0, stream>>>(zr, zi, Zh, Zl);
    convW_kernel<<<dim3(64, 96), dim3(32, 8), 0, stream>>>(Wq_r, Wq_i, Wk_r, Wk_i, Wv_r, Wv_i, Wth, Wtl);

    // qk-proj: C[:, 0..2047] = Z * Wt[0..2047]^T  (bf16x3, hi/lo out)
    gemm_bt<1,1><<<dim3(16, 64, 1), b256, 0, stream>>>(
        Zh, Zl, 0, 2048,
        Wth, Wtl, 0, 2048,
        nullptr, Chi, Clo, 0, 3072, 1, 2048/64);

    // v-proj: C[:, 2048..2559] = Z * Wt[2048..2559]^T  (plain bf16, hi only)
    gemm_bt<0,4><<<dim3(4, 64, 1), b256, 0, stream>>>(
        Zh, nullptr, 0, 2048,
        Wth + (size_t)2048*2048, nullptr, 0, 2048,
        nullptr, Chi + 2048, nullptr, 0, 3072, 1, 2048/64);
    if (interleaved)
        gemm_bt<0,4><<<dim3(4, 64, 1), b256, 0, stream>>>(
            Zh, nullptr, 0, 2048,
            Wth + (size_t)2560*2048, nullptr, 0, 2048,
            nullptr, Chi + 2560, nullptr, 0, 3072, 1, 2048/64);

    // fused dual score + hybrid: y -> attn region
    score2_kernel<<<dim3(16, 16, 4), b256, 0, stream>>>(Chi, Clo, attn);

    // Vt: vr (cols 2048..2559) transposed per batch
    vt_kernel<<<dim3(64, 16, 4), dim3(32, 8), 0, stream>>>(Chi, 2048, Vt);
    if (interleaved)
        vt_kernel<<<dim3(64, 16, 4), dim3(32, 8), 0, stream>>>(Chi, 2560, Vti);

    softmax_kernel<<<8192, b256, 0, stream>>>(attn, Wbf);

    // PV: out[s][d] = sum_t W[s][t] * vr[t][d]  == Wbf * Vt^T
    if (!interleaved){
        gemm_bt<0,0><<<dim3(4, 16, 4), b256, 0, stream>>>(
            Wbf, nullptr, 2048LL*2048, 2048,
            Vt, nullptr, 512LL*2048, 2048,
            outP, nullptr, nullptr, 2048LL*512, 512, 1, 2048/64);
    } else {
        gemm_bt<0,0><<<dim3(4, 16, 4), b256, 0, stream>>>(
            Wbf, nullptr, 2048LL*2048, 2048,
            Vt, nullptr, 512LL*2048, 2048,
            outP, nullptr, nullptr, 2048LL*512*2, 512, 2, 2048/64);
        gemm_bt<0,0><<<dim3(4, 16, 4), b256, 0, stream>>>(
            Wbf, nullptr, 2048LL*2048, 2048,
            Vti, nullptr, 512LL*2048, 2048,
            outP + 1, nullptr, nullptr, 2048LL*512*2, 512, 2, 2048/64);
    }
    (void)in_sizes; (void)n_in; (void)ws_size;
}